// Round 7
// baseline (91.763 us; speedup 1.0000x reference)
//
#include <hip/hip_runtime.h>

typedef unsigned short ushort_t;
typedef unsigned int uint_t;

constexpr int BSZ = 32;
constexpr int CH  = 64;
constexpr int HW  = 32 * 128;   // 4096
constexpr int NP  = 512;
constexpr int OSPLIT = 2;             // o-loop split across blocks
constexpr int OCHUNK = NP / OSPLIT;   // 256
constexpr float EPS = 1e-8f;

using short8 = __attribute__((ext_vector_type(8))) short;   // 8 bf16 (4 VGPRs)
using f32x4  = __attribute__((ext_vector_type(4))) float;

__device__ __forceinline__ ushort_t f2bf(float f) {   // fp32 -> bf16 RNE
    uint_t u = __builtin_bit_cast(uint_t, f);
    u += 0x7FFFu + ((u >> 16) & 1u);
    return (ushort_t)(u >> 16);
}
__device__ __forceinline__ float bf2f(ushort_t b) {
    uint_t u = ((uint_t)b) << 16;
    return __builtin_bit_cast(float, u);
}
__device__ __forceinline__ float tanh_fast(float x) {
    // tanh(x) = 1 - 2/(exp2(2*log2e*x)+1)
    float e = __builtin_amdgcn_exp2f(x * 2.8853900817779268f);
    float r = __builtin_amdgcn_rcpf(e + 1.0f);
    return fmaf(-2.0f, r, 1.0f);
}

// K0: split W into bf16 hi/lo; fold Ua_b+query into QB.
__global__ __launch_bounds__(256) void k_prep(
    const float* __restrict__ Ua_w, const float* __restrict__ Ua_b,
    const float* __restrict__ query,
    ushort_t* __restrict__ Whi, ushort_t* __restrict__ Wlo,
    float* __restrict__ QB)
{
    const int i = blockIdx.x * 256 + threadIdx.x;
    if (i < NP * CH) {
        float x = Ua_w[i];
        ushort_t h = f2bf(x);
        Whi[i] = h;
        Wlo[i] = f2bf(x - bf2f(h));
    }
    if (i < BSZ * NP) {
        QB[i] = query[i] + Ua_b[i & (NP - 1)];
    }
}

// K1: partial logits, MFMA 16x16x32 bf16, 3-pass bf16 split.
// nt=2 (32 positions/wave) with SPLIT hi/lo accumulators: accA takes the
// three ks=0 MFMA terms, accB the three ks=1 terms -> 4 independent chains
// of depth 3 (latency cover of round-3's nt=4) at HALF the B-frag VGPRs.
// Round 6 evidence: nt=4's 64 B-VGPRs lose the regalloc fight (VGPR=84
// reported, 16 MB scratch writes) and 1024 blocks at 3/CU leave a 33% tail.
// Here: ~110 VGPR <= 128 cap at (256,4); grid 2048 = exactly 2 rounds of
// 4 blocks/CU.
__global__ __launch_bounds__(256, 4) void k_scores(
    const float* __restrict__ key,
    const ushort_t* __restrict__ Whi, const ushort_t* __restrict__ Wlo,
    const float* __restrict__ QB, const float* __restrict__ Va_w,
    float* __restrict__ e_part)
{
    const int bx = blockIdx.x;            // 0..2047
    const int pc = bx & 31;               // position chunk (128 pos each)
    const int b  = (bx >> 5) & 31;        // batch
    const int r  = bx >> 10;              // o-half
    const int wv = threadIdx.x >> 6;
    const int l  = threadIdx.x & 63;
    const int lm = l & 15;                // col-in-tile (A row / B,C col)
    const int kg = l >> 4;                // k-group
    const int p0 = pc * 128 + wv * 32;    // wave's first position

    // ---- load + bf16-split this wave's B = key[b, :, p0..p0+31] ----
    // B-frag layout: col = l&15, k = kg*8 + j  (within each K=32 step)
    short8 Bh[2][2], Bl[2][2];
    const float* kb = key + (size_t)b * CH * HW;
#pragma unroll
    for (int nt = 0; nt < 2; ++nt) {
#pragma unroll
        for (int ks = 0; ks < 2; ++ks) {
#pragma unroll
            for (int j = 0; j < 8; ++j) {
                float x = kb[(size_t)(ks * 32 + kg * 8 + j) * HW + (p0 + nt * 16 + lm)];
                ushort_t h = f2bf(x);
                Bh[nt][ks][j] = (short)h;
                Bl[nt][ks][j] = (short)f2bf(x - bf2f(h));
            }
        }
    }

    const float* qbp = QB + b * NP + r * OCHUNK;
    const float* vwp = Va_w + r * OCHUNK;
    const ushort_t* whp = Whi + r * OCHUNK * CH;
    const ushort_t* wlp = Wlo + r * OCHUNK * CH;

    float ew[2] = {0.0f, 0.0f};

    // software pipeline: prefetch m-tile 0
    int arow = lm * CH + kg * 8;
    short8 nAh0 = *(const short8*)(whp + arow);
    short8 nAh1 = *(const short8*)(whp + arow + 32);
    short8 nAl0 = *(const short8*)(wlp + arow);
    short8 nAl1 = *(const short8*)(wlp + arow + 32);
    f32x4 nqb = *(const f32x4*)(qbp + kg * 4);
    f32x4 nvw = *(const f32x4*)(vwp + kg * 4);

    for (int mt = 0; mt < OCHUNK / 16; ++mt) {
        const short8 Ah0 = nAh0, Ah1 = nAh1, Al0 = nAl0, Al1 = nAl1;
        const f32x4 qb = nqb, vw = nvw;
        if (mt + 1 < OCHUNK / 16) {       // prefetch m-tile mt+1
            arow = ((mt + 1) * 16 + lm) * CH + kg * 8;
            nAh0 = *(const short8*)(whp + arow);
            nAh1 = *(const short8*)(whp + arow + 32);
            nAl0 = *(const short8*)(wlp + arow);
            nAl1 = *(const short8*)(wlp + arow + 32);
            nqb = *(const f32x4*)(qbp + (mt + 1) * 16 + kg * 4);
            nvw = *(const f32x4*)(vwp + (mt + 1) * 16 + kg * 4);
        }

        // 4 independent chains of depth 3: {nt0,nt1} x {accA(ks=0), accB(ks=1)}
        f32x4 accA[2], accB[2];
#pragma unroll
        for (int nt = 0; nt < 2; ++nt) {
            accA[nt] = (f32x4){0.f, 0.f, 0.f, 0.f};
            accB[nt] = (f32x4){0.f, 0.f, 0.f, 0.f};
        }
#pragma unroll
        for (int nt = 0; nt < 2; ++nt) {
            accA[nt] = __builtin_amdgcn_mfma_f32_16x16x32_bf16(Ah0, Bh[nt][0], accA[nt], 0, 0, 0);
            accB[nt] = __builtin_amdgcn_mfma_f32_16x16x32_bf16(Ah1, Bh[nt][1], accB[nt], 0, 0, 0);
            accA[nt] = __builtin_amdgcn_mfma_f32_16x16x32_bf16(Ah0, Bl[nt][0], accA[nt], 0, 0, 0);
            accB[nt] = __builtin_amdgcn_mfma_f32_16x16x32_bf16(Ah1, Bl[nt][1], accB[nt], 0, 0, 0);
            accA[nt] = __builtin_amdgcn_mfma_f32_16x16x32_bf16(Al0, Bh[nt][0], accA[nt], 0, 0, 0);
            accB[nt] = __builtin_amdgcn_mfma_f32_16x16x32_bf16(Al1, Bh[nt][1], accB[nt], 0, 0, 0);
        }

        // C/D layout: col = l&15, row = kg*4 + rr  ->  o = mt*16 + kg*4 + rr
#pragma unroll
        for (int nt = 0; nt < 2; ++nt) {
#pragma unroll
            for (int rr = 0; rr < 4; ++rr) {
                float s = (accA[nt][rr] + accB[nt][rr]) + qb[rr];
                ew[nt] = fmaf(vw[rr], tanh_fast(s), ew[nt]);
            }
        }
    }

    // reduce over the 4 k-groups (rows live in lanes l, l^16, l^32, l^48)
#pragma unroll
    for (int nt = 0; nt < 2; ++nt) {
        ew[nt] += __shfl_xor(ew[nt], 16, 64);
        ew[nt] += __shfl_xor(ew[nt], 32, 64);
    }
    if (kg == 0) {
#pragma unroll
        for (int nt = 0; nt < 2; ++nt)
            e_part[(size_t)r * (BSZ * HW) + (size_t)b * HW + p0 + nt * 16 + lm] = ew[nt];
    }
}

// K2: combine o-halves, exp, per-batch denominator.
__global__ __launch_bounds__(256) void k_denom(
    const float* __restrict__ e_part,
    const float* __restrict__ Va_b,
    float* __restrict__ e_exp,
    float* __restrict__ inv_denom)
{
    const int b = blockIdx.x;
    const int tid = threadIdx.x;
    const float vb = Va_b[0];
    float s = 0.0f;
#pragma unroll
    for (int i = 0; i < HW / 256; ++i) {
        const int idx = b * HW + i * 256 + tid;
        float e = __expf((e_part[idx] + e_part[BSZ * HW + idx]) + vb);
        e_exp[idx] = e;
        s += e;
    }
#pragma unroll
    for (int off = 32; off > 0; off >>= 1) s += __shfl_down(s, off, 64);
    __shared__ float wsum[4];
    if ((tid & 63) == 0) wsum[tid >> 6] = s;
    __syncthreads();
    if (tid == 0) {
        float t = (wsum[0] + wsum[1]) + (wsum[2] + wsum[3]);
        inv_denom[b] = 1.0f / (t + EPS);
    }
}

// K3: out[b,c,p] = feature[b,c,p] * e_exp[b,p] * inv_denom[b]  (float4)
__global__ __launch_bounds__(256) void k_scale(
    const float* __restrict__ feature,
    const float* __restrict__ e_exp,
    const float* __restrict__ inv_denom,
    float* __restrict__ out)
{
    const int idx = blockIdx.x * 256 + threadIdx.x;   // float4 index
    const int pq = idx & (HW / 4 - 1);
    const int bc = idx >> 10;
    const int b  = bc >> 6;

    const float sc = inv_denom[b];
    const float4 e = ((const float4*)(e_exp + (size_t)b * HW))[pq];
    const float4 f = ((const float4*)feature)[idx];
    float4 o;
    o.x = f.x * (e.x * sc);
    o.y = f.y * (e.y * sc);
    o.z = f.z * (e.z * sc);
    o.w = f.w * (e.w * sc);
    ((float4*)out)[idx] = o;
}

extern "C" void kernel_launch(void* const* d_in, const int* in_sizes, int n_in,
                              void* d_out, int out_size, void* d_ws, size_t ws_size,
                              hipStream_t stream)
{
    const float* feature = (const float*)d_in[0];
    const float* query   = (const float*)d_in[1];
    const float* key     = (const float*)d_in[2];
    const float* Ua_w    = (const float*)d_in[3];
    const float* Ua_b    = (const float*)d_in[4];
    const float* Va_w    = (const float*)d_in[5];
    const float* Va_b    = (const float*)d_in[6];

    // workspace layout
    ushort_t* Whi = (ushort_t*)d_ws;                        // 512*64
    ushort_t* Wlo = Whi + NP * CH;                          // 512*64
    float* QB     = (float*)(Wlo + NP * CH);                // 32*512
    float* e_part = QB + BSZ * NP;                          // OSPLIT*32*4096
    float* e_exp  = e_part + (size_t)OSPLIT * BSZ * HW;     // 32*4096
    float* inv_denom = e_exp + BSZ * HW;                    // 32

    k_prep<<<(NP * CH) / 256, 256, 0, stream>>>(Ua_w, Ua_b, query, Whi, Wlo, QB);
    k_scores<<<BSZ * (HW / 128) * OSPLIT, 256, 0, stream>>>(
        key, Whi, Wlo, QB, Va_w, e_part);
    k_denom<<<BSZ, 256, 0, stream>>>(e_part, Va_b, e_exp, inv_denom);
    k_scale<<<(BSZ * CH * HW / 4) / 256, 256, 0, stream>>>(
        feature, e_exp, inv_denom, (float*)d_out);
}

// Round 8
// 67.620 us; speedup vs baseline: 1.3570x; 1.3570x over previous
//
#include <hip/hip_runtime.h>

typedef unsigned short ushort_t;
typedef unsigned int uint_t;

constexpr int BSZ = 32;
constexpr int CH  = 64;
constexpr int HW  = 32 * 128;   // 4096
constexpr int NP  = 512;
constexpr int OSPLIT = 4;             // o-loop split across blocks
constexpr int OCHUNK = NP / OSPLIT;   // 128
constexpr int MT     = OCHUNK / 16;   // 8 m-tiles per block
constexpr float EPS = 1e-8f;

using short8 = __attribute__((ext_vector_type(8))) short;   // 8 bf16 (4 VGPRs)
using f32x4  = __attribute__((ext_vector_type(4))) float;

__device__ __forceinline__ ushort_t f2bf(float f) {   // fp32 -> bf16 RNE
    uint_t u = __builtin_bit_cast(uint_t, f);
    u += 0x7FFFu + ((u >> 16) & 1u);
    return (ushort_t)(u >> 16);
}
__device__ __forceinline__ float bf2f(ushort_t b) {
    uint_t u = ((uint_t)b) << 16;
    return __builtin_bit_cast(float, u);
}
__device__ __forceinline__ float tanh_fast(float x) {
    float e = __builtin_amdgcn_exp2f(x * 2.8853900817779268f);
    float r = __builtin_amdgcn_rcpf(e + 1.0f);
    return fmaf(-2.0f, r, 1.0f);
}

// async global->LDS, 16B/lane and 4B/lane (size must be a literal)
__device__ __forceinline__ void gld16(const void* g, void* l) {
    __builtin_amdgcn_global_load_lds(
        (const __attribute__((address_space(1))) void*)g,
        (__attribute__((address_space(3))) void*)l, 16, 0, 0);
}
__device__ __forceinline__ void gld4(const void* g, void* l) {
    __builtin_amdgcn_global_load_lds(
        (const __attribute__((address_space(1))) void*)g,
        (__attribute__((address_space(3))) void*)l, 4, 0, 0);
}

// K0: split W into bf16 hi/lo written in MFMA-FRAG ORDER so k_scores can
// stage it with linear global_load_lds and read A-frags as one conflict-free
// ds_read_b128 at lane*16. Frag index: o=(r*128+mt*16+lm), ch=(ks*32+kg*8+j)
//   fidx = r*8192 + mt*1024 + ks*512 + (kg*16+lm)*8 + j
// Also folds Ua_b+query into QB.
__global__ __launch_bounds__(256) void k_prep(
    const float* __restrict__ Ua_w, const float* __restrict__ Ua_b,
    const float* __restrict__ query,
    ushort_t* __restrict__ Whi_f, ushort_t* __restrict__ Wlo_f,
    float* __restrict__ QB)
{
    const int i = blockIdx.x * 256 + threadIdx.x;
    if (i < NP * CH) {
        const int o = i >> 6, ch = i & 63;
        const int r = o >> 7, mt = (o >> 4) & 7, lm = o & 15;
        const int ks = ch >> 5, kg = (ch >> 3) & 3, j = ch & 7;
        const int fidx = r * 8192 + mt * 1024 + ks * 512 + (kg * 16 + lm) * 8 + j;
        float x = Ua_w[i];
        ushort_t h = f2bf(x);
        Whi_f[fidx] = h;
        Wlo_f[fidx] = f2bf(x - bf2f(h));
    }
    if (i < BSZ * NP) {
        QB[i] = query[i] + Ua_b[i & (NP - 1)];
    }
}

// K1: partial logits. ZERO vector-memory instructions in the m-tile loop:
// W (frag-order), QB, Va_w live in LDS; key is staged through a 4KB/wave LDS
// bounce (16 coalesced global_load_lds instead of 64 strided dwords) and
// split into B-frag registers once. Round-7 diagnosis: all prior rounds were
// VMEM-instruction-throughput bound (~40cyc/wave-instr at the TA/L1), which
// is why occupancy/spill fixes never moved the needle.
// LDS: 32KB W + 16KB key bounce + 1KB qb/vw = 49.5KB -> 3 blocks/CU.
__global__ __launch_bounds__(256, 3) void k_scores(
    const float* __restrict__ key,
    const ushort_t* __restrict__ Whi_f, const ushort_t* __restrict__ Wlo_f,
    const float* __restrict__ QB, const float* __restrict__ Va_w,
    float* __restrict__ e_part)
{
    const int bx = blockIdx.x;            // 0..2047
    const int r  = bx >> 9;               // o-chunk 0..3
    const int inner = bx & 511;
    const int b  = inner >> 4;            // batch
    const int pc = inner & 15;            // 256-position chunk
    const int wv = threadIdx.x >> 6;
    const int l  = threadIdx.x & 63;
    const int lm = l & 15;                // col-in-tile (A row / B,C col)
    const int kg = l >> 4;                // k-group
    const int p0 = pc * 256 + wv * 64;    // wave's first position

    __shared__ ushort_t Wl[16384];        // [hi 8K | lo 8K] in frag order
    __shared__ float ksc[4][1024];        // per-wave key bounce: [16 ch][64 pos]
    __shared__ float qbl[OCHUNK];
    __shared__ float vwl[OCHUNK];

    const float* kb = key + (size_t)b * CH * HW;

    // ---- issue W staging (async; drained by the first __syncthreads) ----
#pragma unroll
    for (int t = 0; t < 4; ++t) {
        const int i = wv * 4 + t;         // 16 x 1KB chunks of hi
        gld16(Whi_f + (size_t)r * 8192 + i * 512 + l * 8, &Wl[i * 512]);
    }
#pragma unroll
    for (int t = 0; t < 4; ++t) {
        const int i = wv * 4 + t;         // 16 x 1KB chunks of lo
        gld16(Wlo_f + (size_t)r * 8192 + i * 512 + l * 8, &Wl[8192 + i * 512]);
    }
    if (wv == 2) {                        // qb chunk: 128 floats
#pragma unroll
        for (int t = 0; t < 2; ++t)
            gld4(QB + b * NP + r * OCHUNK + t * 64 + l, &qbl[t * 64]);
    }
    if (wv == 3) {                        // vw chunk: 128 floats
#pragma unroll
        for (int t = 0; t < 2; ++t)
            gld4(Va_w + r * OCHUNK + t * 64 + l, &vwl[t * 64]);
    }

    // ---- key -> B-frags via LDS bounce, 4 channel-groups of 16 ----
    // group g holds channels 16g..16g+15 = (ks=g>>1, kg in {2*(g&1), 2*(g&1)+1})
    short8 Bh[4][2], Bl8[4][2];
    for (int g = 0; g < 4; ++g) {
#pragma unroll
        for (int t = 0; t < 4; ++t) {     // 4 x 1KB: 4 channels x 64 pos each
            const int ch = g * 16 + t * 4 + (l >> 4);
            gld16(kb + (size_t)ch * HW + p0 + (l & 15) * 4, &ksc[wv][t * 256]);
        }
        __syncthreads();                  // staging (incl. W on g==0) visible
        if ((kg >> 1) == (g & 1)) {
            const int ks = g >> 1;
            const int c2 = (kg & 1) * 8;
#pragma unroll
            for (int nt = 0; nt < 4; ++nt) {
#pragma unroll
                for (int j = 0; j < 8; ++j) {
                    float x = ksc[wv][(c2 + j) * 64 + nt * 16 + lm];
                    ushort_t h = f2bf(x);
                    Bh[nt][ks][j]  = (short)h;
                    Bl8[nt][ks][j] = (short)f2bf(x - bf2f(h));
                }
            }
        }
        __syncthreads();                  // reads done before region reused
    }

    // ---- m-tile loop: LDS-only operands ----
    float ew[4] = {0.0f, 0.0f, 0.0f, 0.0f};
#pragma unroll 2
    for (int mt = 0; mt < MT; ++mt) {
        const short8 Ah0 = *(const short8*)(&Wl[mt * 1024 + l * 8]);
        const short8 Ah1 = *(const short8*)(&Wl[mt * 1024 + 512 + l * 8]);
        const short8 Al0 = *(const short8*)(&Wl[8192 + mt * 1024 + l * 8]);
        const short8 Al1 = *(const short8*)(&Wl[8192 + mt * 1024 + 512 + l * 8]);
        const f32x4 qb = *(const f32x4*)(&qbl[mt * 16 + kg * 4]);
        const f32x4 vw = *(const f32x4*)(&vwl[mt * 16 + kg * 4]);

        f32x4 acc[4];
#pragma unroll
        for (int nt = 0; nt < 4; ++nt) acc[nt] = (f32x4){0.f, 0.f, 0.f, 0.f};
#pragma unroll
        for (int nt = 0; nt < 4; ++nt) {
            acc[nt] = __builtin_amdgcn_mfma_f32_16x16x32_bf16(Ah0, Bh[nt][0],  acc[nt], 0, 0, 0);
            acc[nt] = __builtin_amdgcn_mfma_f32_16x16x32_bf16(Ah1, Bh[nt][1],  acc[nt], 0, 0, 0);
            acc[nt] = __builtin_amdgcn_mfma_f32_16x16x32_bf16(Ah0, Bl8[nt][0], acc[nt], 0, 0, 0);
            acc[nt] = __builtin_amdgcn_mfma_f32_16x16x32_bf16(Ah1, Bl8[nt][1], acc[nt], 0, 0, 0);
            acc[nt] = __builtin_amdgcn_mfma_f32_16x16x32_bf16(Al0, Bh[nt][0],  acc[nt], 0, 0, 0);
            acc[nt] = __builtin_amdgcn_mfma_f32_16x16x32_bf16(Al1, Bh[nt][1],  acc[nt], 0, 0, 0);
        }

        // C/D: col = lm, row = kg*4 + rr  ->  o = r*128 + mt*16 + kg*4 + rr
#pragma unroll
        for (int nt = 0; nt < 4; ++nt) {
#pragma unroll
            for (int rr = 0; rr < 4; ++rr) {
                float s = acc[nt][rr] + qb[rr];
                ew[nt] = fmaf(vw[rr], tanh_fast(s), ew[nt]);
            }
        }
    }

    // reduce over the 4 k-groups (rows live in lanes l, l^16, l^32, l^48)
#pragma unroll
    for (int nt = 0; nt < 4; ++nt) {
        ew[nt] += __shfl_xor(ew[nt], 16, 64);
        ew[nt] += __shfl_xor(ew[nt], 32, 64);
    }
    if (kg == 0) {
#pragma unroll
        for (int nt = 0; nt < 4; ++nt)
            e_part[(size_t)r * (BSZ * HW) + (size_t)b * HW + p0 + nt * 16 + lm] = ew[nt];
    }
}

// K2: combine 4 o-chunks, exp, per-batch denominator.
__global__ __launch_bounds__(256) void k_denom(
    const float* __restrict__ e_part,
    const float* __restrict__ Va_b,
    float* __restrict__ e_exp,
    float* __restrict__ inv_denom)
{
    const int b = blockIdx.x;
    const int tid = threadIdx.x;
    const float vb = Va_b[0];
    float s = 0.0f;
#pragma unroll
    for (int i = 0; i < HW / 256; ++i) {
        const int idx = b * HW + i * 256 + tid;
        float et = ((e_part[idx] + e_part[BSZ * HW + idx]) +
                    (e_part[2 * BSZ * HW + idx] + e_part[3 * BSZ * HW + idx])) + vb;
        float e = __expf(et);
        e_exp[idx] = e;
        s += e;
    }
#pragma unroll
    for (int off = 32; off > 0; off >>= 1) s += __shfl_down(s, off, 64);
    __shared__ float wsum[4];
    if ((tid & 63) == 0) wsum[tid >> 6] = s;
    __syncthreads();
    if (tid == 0) {
        float t = (wsum[0] + wsum[1]) + (wsum[2] + wsum[3]);
        inv_denom[b] = 1.0f / (t + EPS);
    }
}

// K3: out[b,c,p] = feature[b,c,p] * e_exp[b,p] * inv_denom[b]  (float4)
__global__ __launch_bounds__(256) void k_scale(
    const float* __restrict__ feature,
    const float* __restrict__ e_exp,
    const float* __restrict__ inv_denom,
    float* __restrict__ out)
{
    const int idx = blockIdx.x * 256 + threadIdx.x;   // float4 index
    const int pq = idx & (HW / 4 - 1);
    const int bc = idx >> 10;
    const int b  = bc >> 6;

    const float sc = inv_denom[b];
    const float4 e = ((const float4*)(e_exp + (size_t)b * HW))[pq];
    const float4 f = ((const float4*)feature)[idx];
    float4 o;
    o.x = f.x * (e.x * sc);
    o.y = f.y * (e.y * sc);
    o.z = f.z * (e.z * sc);
    o.w = f.w * (e.w * sc);
    ((float4*)out)[idx] = o;
}

extern "C" void kernel_launch(void* const* d_in, const int* in_sizes, int n_in,
                              void* d_out, int out_size, void* d_ws, size_t ws_size,
                              hipStream_t stream)
{
    const float* feature = (const float*)d_in[0];
    const float* query   = (const float*)d_in[1];
    const float* key     = (const float*)d_in[2];
    const float* Ua_w    = (const float*)d_in[3];
    const float* Ua_b    = (const float*)d_in[4];
    const float* Va_w    = (const float*)d_in[5];
    const float* Va_b    = (const float*)d_in[6];

    // workspace layout
    ushort_t* Whi_f = (ushort_t*)d_ws;                      // 512*64 frag-order
    ushort_t* Wlo_f = Whi_f + NP * CH;                      // 512*64
    float* QB     = (float*)(Wlo_f + NP * CH);              // 32*512
    float* e_part = QB + BSZ * NP;                          // OSPLIT*32*4096
    float* e_exp  = e_part + (size_t)OSPLIT * BSZ * HW;     // 32*4096
    float* inv_denom = e_exp + BSZ * HW;                    // 32

    k_prep<<<(NP * CH) / 256, 256, 0, stream>>>(Ua_w, Ua_b, query, Whi_f, Wlo_f, QB);
    k_scores<<<BSZ * (HW / 256) * OSPLIT, 256, 0, stream>>>(
        key, Whi_f, Wlo_f, QB, Va_w, e_part);
    k_denom<<<BSZ, 256, 0, stream>>>(e_part, Va_b, e_exp, inv_denom);
    k_scale<<<(BSZ * CH * HW / 4) / 256, 256, 0, stream>>>(
        feature, e_exp, inv_denom, (float*)d_out);
}

// Round 9
// 55.105 us; speedup vs baseline: 1.6652x; 1.2271x over previous
//
#include <hip/hip_runtime.h>

typedef unsigned short ushort_t;
typedef unsigned int uint_t;

constexpr int BSZ = 32;
constexpr int CH  = 64;
constexpr int HW  = 32 * 128;   // 4096
constexpr int NP  = 512;
constexpr float EPS = 1e-8f;
constexpr float SC  = 2.8853900817779268f;   // 2*log2(e): pre-scales W,QB so tanh skips its mul
constexpr float L2E = 1.4426950408889634f;   // log2(e)

using short8 = __attribute__((ext_vector_type(8))) short;   // 8 bf16 (4 VGPRs)
using f32x4  = __attribute__((ext_vector_type(4))) float;

__device__ __forceinline__ ushort_t f2bf(float f) {   // fp32 -> bf16 RNE
    uint_t u = __builtin_bit_cast(uint_t, f);
    u += 0x7FFFu + ((u >> 16) & 1u);
    return (ushort_t)(u >> 16);
}
__device__ __forceinline__ float bf2f(ushort_t b) {
    uint_t u = ((uint_t)b) << 16;
    return __builtin_bit_cast(float, u);
}

// async global->LDS, 16B/lane (size must be a literal).
// global src is PER-LANE; LDS dest is wave-uniform base + lane*16.
__device__ __forceinline__ void gld16(const void* g, void* l) {
    __builtin_amdgcn_global_load_lds(
        (const __attribute__((address_space(1))) void*)g,
        (__attribute__((address_space(3))) void*)l, 16, 0, 0);
}

// K0: W' = SC*Ua_w split to bf16 hi/lo in MFMA-frag order
//   fidx = r*8192 + mt*1024 + ks*512 + (kg*16+lm)*8 + j
// (o = r*128+mt*16+lm, ch = ks*32+kg*8+j). QB = SC*(query+Ua_b).
__global__ __launch_bounds__(256) void k_prep(
    const float* __restrict__ Ua_w, const float* __restrict__ Ua_b,
    const float* __restrict__ query,
    ushort_t* __restrict__ Whi_f, ushort_t* __restrict__ Wlo_f,
    float* __restrict__ QB)
{
    const int i = blockIdx.x * 256 + threadIdx.x;
    if (i < NP * CH) {
        const int o = i >> 6, ch = i & 63;
        const int r = o >> 7, mt = (o >> 4) & 7, lm = o & 15;
        const int ks = ch >> 5, kg = (ch >> 3) & 3, j = ch & 7;
        const int fidx = r * 8192 + mt * 1024 + ks * 512 + (kg * 16 + lm) * 8 + j;
        float x = Ua_w[i] * SC;
        ushort_t h = f2bf(x);
        Whi_f[fidx] = h;
        Wlo_f[fidx] = f2bf(x - bf2f(h));
    }
    if (i < BSZ * NP) {
        QB[i] = SC * (query[i] + Ua_b[i & (NP - 1)]);
    }
}

// K1: full logit per position + exp, in one kernel.
// Block = (b, 128-pos chunk) -> 1024 blocks = exactly 4/CU at 36KB LDS.
// Wave owns 32 positions; key loaded+split ONCE (round-8 did it 4x); r-loop
// stages the 32KB W chunk per r (8 gld16/wave, L2-resident source).
// nt=2 with split hi/lo accumulators = 4 independent depth-3 MFMA chains.
__global__ __launch_bounds__(256, 4) void k_scores(
    const float* __restrict__ key,
    const ushort_t* __restrict__ Whi_f, const ushort_t* __restrict__ Wlo_f,
    const float* __restrict__ QB, const float* __restrict__ Va_w,
    const float* __restrict__ Va_b,
    float* __restrict__ e_exp)
{
    const int bx = blockIdx.x;            // 0..1023
    const int b  = bx >> 5;               // batch
    const int pc = bx & 31;               // 128-pos chunk
    const int wv = threadIdx.x >> 6;
    const int l  = threadIdx.x & 63;
    const int lm = l & 15;                // col-in-tile (A row / B,C col)
    const int kg = l >> 4;                // k-group
    const int p0 = pc * 128 + wv * 32;    // wave's first position

    __shared__ ushort_t Wl[16384];        // [hi 8K | lo 8K] ushorts, frag order
    __shared__ float qbl[NP];
    __shared__ float vwl[NP];

    // stage qb/vw once (drained by the r=0 barrier)
    if (wv == 0) {
        gld16(QB + b * NP + l * 4,       &qbl[0]);
        gld16(QB + b * NP + 256 + l * 4, &qbl[256]);
    }
    if (wv == 1) {
        gld16(Va_w + l * 4,       &vwl[0]);
        gld16(Va_w + 256 + l * 4, &vwl[256]);
    }

    // ---- load + bf16-split this wave's key ONCE: B = key[b,:,p0..p0+31] ----
    short8 Bh[2][2], Bl8[2][2];
    const float* kb = key + (size_t)b * CH * HW;
#pragma unroll
    for (int nt = 0; nt < 2; ++nt) {
#pragma unroll
        for (int ks = 0; ks < 2; ++ks) {
#pragma unroll
            for (int j = 0; j < 8; ++j) {
                float x = kb[(size_t)(ks * 32 + kg * 8 + j) * HW + (p0 + nt * 16 + lm)];
                ushort_t h = f2bf(x);
                Bh[nt][ks][j]  = (short)h;
                Bl8[nt][ks][j] = (short)f2bf(x - bf2f(h));
            }
        }
    }

    float ew[2] = {0.0f, 0.0f};

    for (int r = 0; r < 4; ++r) {
        // stage W chunk r: 32KB across 4 waves (8 gld16 each)
#pragma unroll
        for (int t = 0; t < 4; ++t) {
            const int c = wv * 4 + t;     // 16 chunks of 512 ushorts
            gld16(Whi_f + (size_t)r * 8192 + c * 512 + l * 8, &Wl[c * 512]);
            gld16(Wlo_f + (size_t)r * 8192 + c * 512 + l * 8, &Wl[8192 + c * 512]);
        }
        __syncthreads();                  // staging visible

        for (int mt = 0; mt < 8; ++mt) {
            const short8 Ah0 = *(const short8*)&Wl[mt * 1024 + l * 8];
            const short8 Ah1 = *(const short8*)&Wl[mt * 1024 + 512 + l * 8];
            const short8 Al0 = *(const short8*)&Wl[8192 + mt * 1024 + l * 8];
            const short8 Al1 = *(const short8*)&Wl[8192 + mt * 1024 + 512 + l * 8];
            const f32x4 qb = *(const f32x4*)&qbl[r * 128 + mt * 16 + kg * 4];
            const f32x4 vw = *(const f32x4*)&vwl[r * 128 + mt * 16 + kg * 4];

            // 4 independent chains of depth 3: {nt0,nt1} x {accA(ks0), accB(ks1)}
            f32x4 accA[2], accB[2];
#pragma unroll
            for (int nt = 0; nt < 2; ++nt) {
                accA[nt] = (f32x4){0.f, 0.f, 0.f, 0.f};
                accB[nt] = (f32x4){0.f, 0.f, 0.f, 0.f};
            }
#pragma unroll
            for (int nt = 0; nt < 2; ++nt) {
                accA[nt] = __builtin_amdgcn_mfma_f32_16x16x32_bf16(Ah0, Bh[nt][0],  accA[nt], 0, 0, 0);
                accB[nt] = __builtin_amdgcn_mfma_f32_16x16x32_bf16(Ah1, Bh[nt][1],  accB[nt], 0, 0, 0);
                accA[nt] = __builtin_amdgcn_mfma_f32_16x16x32_bf16(Ah0, Bl8[nt][0], accA[nt], 0, 0, 0);
                accB[nt] = __builtin_amdgcn_mfma_f32_16x16x32_bf16(Ah1, Bl8[nt][1], accB[nt], 0, 0, 0);
                accA[nt] = __builtin_amdgcn_mfma_f32_16x16x32_bf16(Al0, Bh[nt][0],  accA[nt], 0, 0, 0);
                accB[nt] = __builtin_amdgcn_mfma_f32_16x16x32_bf16(Al1, Bh[nt][1],  accB[nt], 0, 0, 0);
            }

            // C/D: col=lm, row=kg*4+rr -> o = r*128 + mt*16 + kg*4 + rr
            // s is pre-scaled by 2*log2(e): tanh = 1 - 2/(exp2(s)+1)
#pragma unroll
            for (int nt = 0; nt < 2; ++nt) {
#pragma unroll
                for (int rr = 0; rr < 4; ++rr) {
                    float s = (accA[nt][rr] + accB[nt][rr]) + qb[rr];
                    float e = __builtin_amdgcn_exp2f(s);
                    float t = fmaf(-2.0f, __builtin_amdgcn_rcpf(e + 1.0f), 1.0f);
                    ew[nt] = fmaf(vw[rr], t, ew[nt]);
                }
            }
        }
        __syncthreads();                  // all reads done before restage
    }

    // reduce over the 4 k-groups; every lane ends with the full o-sum
#pragma unroll
    for (int nt = 0; nt < 2; ++nt) {
        ew[nt] += __shfl_xor(ew[nt], 16, 64);
        ew[nt] += __shfl_xor(ew[nt], 32, 64);
    }
    const float vb = Va_b[0];
    if (kg == 0) {
#pragma unroll
        for (int nt = 0; nt < 2; ++nt)
            e_exp[(size_t)b * HW + p0 + nt * 16 + lm] =
                __builtin_amdgcn_exp2f((ew[nt] + vb) * L2E);
    }
}

// K2: per-batch denominator only (exp already done in k_scores)
__global__ __launch_bounds__(256) void k_denom(
    const float* __restrict__ e_exp,
    float* __restrict__ inv_denom)
{
    const int b = blockIdx.x;
    const int tid = threadIdx.x;
    const float4* e4 = (const float4*)(e_exp + (size_t)b * HW);
    float s = 0.0f;
#pragma unroll
    for (int i = 0; i < HW / 4 / 256; ++i) {
        float4 v = e4[tid + i * 256];
        s += (v.x + v.y) + (v.z + v.w);
    }
#pragma unroll
    for (int off = 32; off > 0; off >>= 1) s += __shfl_down(s, off, 64);
    __shared__ float wsum[4];
    if ((tid & 63) == 0) wsum[tid >> 6] = s;
    __syncthreads();
    if (tid == 0) {
        float t = (wsum[0] + wsum[1]) + (wsum[2] + wsum[3]);
        inv_denom[b] = 1.0f / (t + EPS);
    }
}

// K3: out[b,c,p] = feature[b,c,p] * e_exp[b,p] * inv_denom[b]  (float4)
__global__ __launch_bounds__(256) void k_scale(
    const float* __restrict__ feature,
    const float* __restrict__ e_exp,
    const float* __restrict__ inv_denom,
    float* __restrict__ out)
{
    const int idx = blockIdx.x * 256 + threadIdx.x;   // float4 index
    const int pq = idx & (HW / 4 - 1);
    const int bc = idx >> 10;
    const int b  = bc >> 6;

    const float sc = inv_denom[b];
    const float4 e = ((const float4*)(e_exp + (size_t)b * HW))[pq];
    const float4 f = ((const float4*)feature)[idx];
    float4 o;
    o.x = f.x * (e.x * sc);
    o.y = f.y * (e.y * sc);
    o.z = f.z * (e.z * sc);
    o.w = f.w * (e.w * sc);
    ((float4*)out)[idx] = o;
}

extern "C" void kernel_launch(void* const* d_in, const int* in_sizes, int n_in,
                              void* d_out, int out_size, void* d_ws, size_t ws_size,
                              hipStream_t stream)
{
    const float* feature = (const float*)d_in[0];
    const float* query   = (const float*)d_in[1];
    const float* key     = (const float*)d_in[2];
    const float* Ua_w    = (const float*)d_in[3];
    const float* Ua_b    = (const float*)d_in[4];
    const float* Va_w    = (const float*)d_in[5];
    const float* Va_b    = (const float*)d_in[6];

    // workspace layout
    ushort_t* Whi_f = (ushort_t*)d_ws;                      // 512*64 frag-order
    ushort_t* Wlo_f = Whi_f + NP * CH;                      // 512*64
    float* QB        = (float*)(Wlo_f + NP * CH);           // 32*512
    float* e_exp     = QB + BSZ * NP;                       // 32*4096
    float* inv_denom = e_exp + BSZ * HW;                    // 32

    k_prep<<<(NP * CH) / 256, 256, 0, stream>>>(Ua_w, Ua_b, query, Whi_f, Wlo_f, QB);
    k_scores<<<BSZ * (HW / 128), 256, 0, stream>>>(
        key, Whi_f, Wlo_f, QB, Va_w, Va_b, e_exp);
    k_denom<<<BSZ, 256, 0, stream>>>(e_exp, inv_denom);
    k_scale<<<(BSZ * CH * HW / 4) / 256, 256, 0, stream>>>(
        feature, e_exp, inv_denom, (float*)d_out);
}